// Round 1
// baseline (958.404 us; speedup 1.0000x reference)
//
#include <hip/hip_runtime.h>
#include <math.h>

#define B_   64
#define MD   1024
#define H_   16
#define D_   64
#define LNEPS 1e-5f

// ---------------------------------------------------------------------------
// ws layout (floats):
//   q      [64][1024]
//   wtil   [64][16][1024]     w̃[b,h,m] = sum_d Wk[m, h*64+d] * q[b,h,d]
//   scores [64][16][sfull]
//   concat [64][1024]
//   integ  [64][1024]
//   fcwt   [1024][1024]       fc_weight transposed
// ---------------------------------------------------------------------------

__device__ __forceinline__ float waveMax(float v) {
    #pragma unroll
    for (int off = 32; off > 0; off >>= 1) v = fmaxf(v, __shfl_xor(v, off, 64));
    return v;
}
__device__ __forceinline__ float waveSum(float v) {
    #pragma unroll
    for (int off = 32; off > 0; off >>= 1) v += __shfl_xor(v, off, 64);
    return v;
}

// ---- Kernel A: q[b, col] = sum_m x[b, idx, m] * Wq[m, col] -----------------
// grid (4 col-chunks, 8 b-groups), block 256
__global__ void k_q(const float* __restrict__ x, const float* __restrict__ wq,
                    const int* __restrict__ idxp, float* __restrict__ qout, int sfull) {
    const int tid = threadIdx.x;
    const int col = blockIdx.x * 256 + tid;
    const int b0  = blockIdx.y * 8;
    const int idx = *idxp;
    float acc[8] = {0,0,0,0,0,0,0,0};
    for (int m = 0; m < MD; ++m) {
        float wv = wq[(size_t)m * MD + col];
        #pragma unroll
        for (int bb = 0; bb < 8; ++bb) {
            // block-uniform address -> scalar load
            float xv = x[((size_t)(b0 + bb) * sfull + idx) * MD + m];
            acc[bb] += xv * wv;
        }
    }
    #pragma unroll
    for (int bb = 0; bb < 8; ++bb)
        qout[(size_t)(b0 + bb) * MD + col] = acc[bb];
}

// ---- Kernel B: wtil[b,h,m] = sum_d Wk[m, h*64+d] * q[b, h*64+d] ------------
// grid (16 h, 8 b-groups), block 256
__global__ void k_wtil(const float* __restrict__ wk, const float* __restrict__ q,
                       float* __restrict__ wtil) {
    const int tid = threadIdx.x;
    const int h  = blockIdx.x;
    const int b0 = blockIdx.y * 8;
    for (int mi = 0; mi < 4; ++mi) {
        const int m = mi * 256 + tid;
        const float4* wrow = (const float4*)(wk + (size_t)m * MD + h * D_);
        float4 wv[16];
        #pragma unroll
        for (int j = 0; j < 16; ++j) wv[j] = wrow[j];
        #pragma unroll
        for (int bb = 0; bb < 8; ++bb) {
            const float* qh = q + (size_t)(b0 + bb) * MD + h * D_;  // uniform -> s_load
            float acc = 0.f;
            #pragma unroll
            for (int j = 0; j < 16; ++j)
                acc += wv[j].x * qh[4*j] + wv[j].y * qh[4*j+1]
                     + wv[j].z * qh[4*j+2] + wv[j].w * qh[4*j+3];
            wtil[((size_t)(b0 + bb) * H_ + h) * MD + m] = acc;
        }
    }
}

// ---- Kernel P1: scores[b,h,s] = (x[b,s,:] . wtil[b,h,:]) / 8 ---------------
// grid (sfull/256 s-tiles, 64 b), block 256. Streams all of x exactly once.
__global__ __launch_bounds__(256) void k_scores(
        const float* __restrict__ x, const float* __restrict__ wtil,
        const int* __restrict__ idxp, float* __restrict__ scores, int sfull) {
    __shared__ float4 X4[256 * 8];   // 32 KB, XOR-swizzled: [row][unit ^ (row&7)]
    const int tid = threadIdx.x;
    const int b   = blockIdx.y;
    const int s0  = blockIdx.x * 256;
    const int S   = *idxp + 1;
    if (s0 >= S) return;

    float acc[16];
    #pragma unroll
    for (int h = 0; h < 16; ++h) acc[h] = 0.f;

    const float* xb = x    + (size_t)b * sfull * MD;
    const float* wb = wtil + (size_t)b * H_ * MD;

    for (int mc = 0; mc < MD; mc += 32) {
        // stage 256 rows x 32 floats, coalesced global, swizzled LDS
        #pragma unroll
        for (int i = 0; i < 8; ++i) {
            int flat = i * 256 + tid;
            int sl = flat >> 3;
            int f4 = flat & 7;
            int srow = s0 + sl;
            float4 v = make_float4(0.f, 0.f, 0.f, 0.f);
            if (srow < S)
                v = *(const float4*)(xb + (size_t)srow * MD + mc + f4 * 4);
            X4[sl * 8 + (f4 ^ (sl & 7))] = v;
        }
        __syncthreads();
        #pragma unroll
        for (int mm4 = 0; mm4 < 8; ++mm4) {
            float4 xv = X4[tid * 8 + (mm4 ^ (tid & 7))];
            #pragma unroll
            for (int h = 0; h < 16; ++h) {
                const float* w = wb + h * MD + mc + mm4 * 4;  // uniform -> s_load_dwordx4
                acc[h] += xv.x * w[0] + xv.y * w[1] + xv.z * w[2] + xv.w * w[3];
            }
        }
        __syncthreads();
    }

    const int s = s0 + tid;
    if (s < S) {
        #pragma unroll
        for (int h = 0; h < 16; ++h)
            scores[((size_t)b * H_ + h) * sfull + s] = acc[h] * 0.125f;
    }
}

// ---- Kernel C: softmax over s + sparse gather y = attn^T x + Wv projection -
// grid (16 h, 64 b), block 256
__global__ void k_attn(const float* __restrict__ x, const float* __restrict__ scores,
                       const float* __restrict__ wv, const int* __restrict__ idxp,
                       float* __restrict__ concat, int sfull) {
    __shared__ float red[8];
    __shared__ int   scan[256];
    __shared__ int   lidx[4096];
    __shared__ float lw[4096];
    __shared__ float ylds[1024];
    __shared__ float pred[256];

    const int tid = threadIdx.x;
    const int h = blockIdx.x, b = blockIdx.y;
    const int S = *idxp + 1;
    const float* sc = scores + ((size_t)b * H_ + h) * sfull;

    float ls[16];
    float mx = -INFINITY;
    #pragma unroll
    for (int k = 0; k < 16; ++k) {
        int s = tid + 256 * k;
        if (s < S) { ls[k] = sc[s]; mx = fmaxf(mx, ls[k]); }
        else ls[k] = -INFINITY;
    }
    // block max
    mx = waveMax(mx);
    const int wid = tid >> 6, lane = tid & 63;
    if (lane == 0) red[wid] = mx;
    __syncthreads();
    mx = fmaxf(fmaxf(red[0], red[1]), fmaxf(red[2], red[3]));

    // denom + significant count (exp(s-max) <= 1.7e-15 contributes nothing)
    float sum = 0.f; int cnt = 0;
    #pragma unroll
    for (int k = 0; k < 16; ++k) {
        if (ls[k] > -INFINITY) {
            float e = ls[k] - mx;
            sum += expf(e);
            if (e > -34.f) ++cnt;
        }
    }
    sum = waveSum(sum);
    __syncthreads();
    if (lane == 0) red[4 + wid] = sum;
    __syncthreads();
    const float inv = 1.f / (red[4] + red[5] + red[6] + red[7]);

    // deterministic compaction: exclusive scan of per-thread counts
    scan[tid] = cnt;
    __syncthreads();
    for (int off = 1; off < 256; off <<= 1) {
        int v = (tid >= off) ? scan[tid - off] : 0;
        __syncthreads();
        scan[tid] += v;
        __syncthreads();
    }
    const int total = scan[255];
    int pos = scan[tid] - cnt;
    #pragma unroll
    for (int k = 0; k < 16; ++k) {
        if (ls[k] > -INFINITY) {
            float e = ls[k] - mx;
            if (e > -34.f) { lidx[pos] = tid + 256 * k; lw[pos] = expf(e) * inv; ++pos; }
        }
    }
    __syncthreads();

    // y[m] = sum_{significant s} attn * x[b,s,m]  (typically 1-3 rows)
    float4 acc = make_float4(0.f, 0.f, 0.f, 0.f);
    const float* xb = x + (size_t)b * sfull * MD;
    for (int e = 0; e < total; ++e) {
        int s = lidx[e]; float w = lw[e];
        float4 xv = *(const float4*)(xb + (size_t)s * MD + tid * 4);
        acc.x += w * xv.x; acc.y += w * xv.y; acc.z += w * xv.z; acc.w += w * xv.w;
    }
    *(float4*)(&ylds[tid * 4]) = acc;
    __syncthreads();

    // head_out[d] = sum_m y[m] * Wv[m, h*64+d]
    const int d = tid & 63, g = tid >> 6;
    const float* wcol = wv + (size_t)h * D_ + d;
    float part = 0.f;
    for (int m = g * 256; m < g * 256 + 256; ++m)
        part += ylds[m] * wcol[(size_t)m * MD];
    pred[tid] = part;
    __syncthreads();
    if (tid < 64) {
        float v = pred[tid] + pred[tid + 64] + pred[tid + 128] + pred[tid + 192];
        concat[(size_t)b * MD + h * D_ + tid] = v;
    }
}

// ---- Kernel T: fcwt[m][n] = fcW[n][m] --------------------------------------
__global__ void k_transpose(const float* __restrict__ a, float* __restrict__ at) {
    __shared__ float t[32][33];
    const int bx = blockIdx.x * 32, by = blockIdx.y * 32;
    const int tx = threadIdx.x & 31, ty = threadIdx.x >> 5;  // 32x8
    for (int r = ty; r < 32; r += 8)
        t[r][tx] = a[(size_t)(by + r) * MD + bx + tx];
    __syncthreads();
    for (int r = ty; r < 32; r += 8)
        at[(size_t)(bx + r) * MD + by + tx] = t[tx][r];
}

// ---- Kernel D: integ[b,n] = sum_m concat[b,m] * fcW[n,m] + bias[n] ---------
// grid 64 (b), block 256; rank-1 over fcwt rows (coalesced)
__global__ void k_fc(const float* __restrict__ concat, const float* __restrict__ fcwt,
                     const float* __restrict__ bias, float* __restrict__ integ) {
    __shared__ float c[1024];
    const int tid = threadIdx.x, b = blockIdx.x;
    #pragma unroll
    for (int k = 0; k < 4; ++k) c[tid + 256 * k] = concat[(size_t)b * MD + tid + 256 * k];
    __syncthreads();
    float acc[4] = {0, 0, 0, 0};
    for (int m = 0; m < MD; ++m) {
        float cm = c[m];
        #pragma unroll
        for (int k = 0; k < 4; ++k)
            acc[k] += cm * fcwt[(size_t)m * MD + tid + 256 * k];
    }
    #pragma unroll
    for (int k = 0; k < 4; ++k)
        integ[(size_t)b * MD + tid + 256 * k] = acc[k] + bias[tid + 256 * k];
}

// ---- Kernel E: LayerNorm ---------------------------------------------------
__global__ void k_ln(const float* __restrict__ integ, const float* __restrict__ gamma,
                     const float* __restrict__ beta, float* __restrict__ out) {
    __shared__ float red[8];
    const int tid = threadIdx.x, b = blockIdx.x;
    float v[4];
    #pragma unroll
    for (int k = 0; k < 4; ++k) v[k] = integ[(size_t)b * MD + tid + 256 * k];
    float s = v[0] + v[1] + v[2] + v[3];
    s = waveSum(s);
    const int wid = tid >> 6, lane = tid & 63;
    if (lane == 0) red[wid] = s;
    __syncthreads();
    const float mean = (red[0] + red[1] + red[2] + red[3]) * (1.f / MD);
    float q = 0.f;
    #pragma unroll
    for (int k = 0; k < 4; ++k) { float d = v[k] - mean; q += d * d; }
    q = waveSum(q);
    __syncthreads();
    if (lane == 0) red[4 + wid] = q;
    __syncthreads();
    const float var = (red[4] + red[5] + red[6] + red[7]) * (1.f / MD);
    const float rs = rsqrtf(var + LNEPS);
    #pragma unroll
    for (int k = 0; k < 4; ++k) {
        int i = tid + 256 * k;
        out[(size_t)b * MD + i] = (v[k] - mean) * rs * gamma[i] + beta[i];
    }
}

extern "C" void kernel_launch(void* const* d_in, const int* in_sizes, int n_in,
                              void* d_out, int out_size, void* d_ws, size_t ws_size,
                              hipStream_t stream) {
    const float* x     = (const float*)d_in[0];
    const float* wq    = (const float*)d_in[1];
    const float* wk    = (const float*)d_in[2];
    const float* wvp   = (const float*)d_in[3];
    const float* fcw   = (const float*)d_in[4];
    const float* fcb   = (const float*)d_in[5];
    const float* gamma = (const float*)d_in[6];
    const float* beta  = (const float*)d_in[7];
    const int*   idxp  = (const int*)d_in[8];
    float* out = (float*)d_out;

    const int sfull = in_sizes[0] / (B_ * MD);   // 4096

    float* q      = (float*)d_ws;
    float* wtil   = q      + (size_t)B_ * MD;
    float* scores = wtil   + (size_t)B_ * H_ * MD;
    float* concat = scores + (size_t)B_ * H_ * sfull;
    float* integ  = concat + (size_t)B_ * MD;
    float* fcwt   = integ  + (size_t)B_ * MD;

    hipLaunchKernelGGL(k_q,         dim3(4, 8),            dim3(256), 0, stream, x, wq, idxp, q, sfull);
    hipLaunchKernelGGL(k_wtil,      dim3(16, 8),           dim3(256), 0, stream, wk, q, wtil);
    hipLaunchKernelGGL(k_scores,    dim3((sfull + 255) / 256, B_), dim3(256), 0, stream, x, wtil, idxp, scores, sfull);
    hipLaunchKernelGGL(k_transpose, dim3(32, 32),          dim3(256), 0, stream, fcw, fcwt);
    hipLaunchKernelGGL(k_attn,      dim3(H_, B_),          dim3(256), 0, stream, x, scores, wvp, idxp, concat, sfull);
    hipLaunchKernelGGL(k_fc,        dim3(B_),              dim3(256), 0, stream, concat, fcwt, fcb, integ);
    hipLaunchKernelGGL(k_ln,        dim3(B_),              dim3(256), 0, stream, integ, gamma, beta, out);
}

// Round 2
// 789.856 us; speedup vs baseline: 1.2134x; 1.2134x over previous
//
#include <hip/hip_runtime.h>
#include <math.h>

#define B_   64
#define MD   1024
#define H_   16
#define D_   64
#define LNEPS 1e-5f

// ---------------------------------------------------------------------------
// ws layout (floats):
//   q      [64][1024]
//   wtil   [64][16][1024]     w̃[b,h,m] = sum_d Wk[m, h*64+d] * q[b,h,d]
//   scores [64][16][sfull]
//   concat [64][1024]
//   integ  [64][1024]
//   fcwt   [1024][1024]       fc_weight transposed
// ---------------------------------------------------------------------------

__device__ __forceinline__ float waveMax(float v) {
    #pragma unroll
    for (int off = 32; off > 0; off >>= 1) v = fmaxf(v, __shfl_xor(v, off, 64));
    return v;
}
__device__ __forceinline__ float waveSum(float v) {
    #pragma unroll
    for (int off = 32; off > 0; off >>= 1) v += __shfl_xor(v, off, 64);
    return v;
}

// ---- Kernel A: q[b, col] = sum_m x[b, idx, m] * Wq[m, col] -----------------
// grid (4 col-chunks, 8 b-groups), block 256
__global__ void k_q(const float* __restrict__ x, const float* __restrict__ wq,
                    const int* __restrict__ idxp, float* __restrict__ qout, int sfull) {
    const int tid = threadIdx.x;
    const int col = blockIdx.x * 256 + tid;
    const int b0  = blockIdx.y * 8;
    const int idx = *idxp;
    float acc[8] = {0,0,0,0,0,0,0,0};
    for (int m = 0; m < MD; ++m) {
        float wv = wq[(size_t)m * MD + col];
        #pragma unroll
        for (int bb = 0; bb < 8; ++bb) {
            // block-uniform address -> scalar load
            float xv = x[((size_t)(b0 + bb) * sfull + idx) * MD + m];
            acc[bb] += xv * wv;
        }
    }
    #pragma unroll
    for (int bb = 0; bb < 8; ++bb)
        qout[(size_t)(b0 + bb) * MD + col] = acc[bb];
}

// ---- Kernel B: wtil[b,h,m] = sum_d Wk[m, h*64+d] * q[b, h*64+d] ------------
// grid (16 h, 8 b-groups), block 256
__global__ void k_wtil(const float* __restrict__ wk, const float* __restrict__ q,
                       float* __restrict__ wtil) {
    const int tid = threadIdx.x;
    const int h  = blockIdx.x;
    const int b0 = blockIdx.y * 8;
    for (int mi = 0; mi < 4; ++mi) {
        const int m = mi * 256 + tid;
        const float4* wrow = (const float4*)(wk + (size_t)m * MD + h * D_);
        float4 wv[16];
        #pragma unroll
        for (int j = 0; j < 16; ++j) wv[j] = wrow[j];
        #pragma unroll
        for (int bb = 0; bb < 8; ++bb) {
            const float* qh = q + (size_t)(b0 + bb) * MD + h * D_;  // uniform -> s_load
            float acc = 0.f;
            #pragma unroll
            for (int j = 0; j < 16; ++j)
                acc += wv[j].x * qh[4*j] + wv[j].y * qh[4*j+1]
                     + wv[j].z * qh[4*j+2] + wv[j].w * qh[4*j+3];
            wtil[((size_t)(b0 + bb) * H_ + h) * MD + m] = acc;
        }
    }
}

// ---- Kernel P1: scores[b,h,s] = (x[b,s,:] . wtil[b,h,:]) / 8 ---------------
// grid (sfull/256 s-tiles, 64 b), block 256. Streams all of x exactly once.
// w-chunk staged in LDS (broadcast ds_read) -- NO per-thread global w loads.
__global__ __launch_bounds__(256) void k_scores(
        const float* __restrict__ x, const float* __restrict__ wtil,
        const int* __restrict__ idxp, float* __restrict__ scores, int sfull) {
    __shared__ float4 X4[256 * 8];   // 32 KB, XOR-swizzled: [row][unit ^ (row&7)]
    __shared__ float4 W4[16 * 8];    // 2 KB: w-tilde[h][mc..mc+32)
    const int tid = threadIdx.x;
    const int b   = blockIdx.y;
    const int s0  = blockIdx.x * 256;
    const int S   = *idxp + 1;
    if (s0 >= S) return;

    float acc[16];
    #pragma unroll
    for (int h = 0; h < 16; ++h) acc[h] = 0.f;

    const float* xb = x    + (size_t)b * sfull * MD;
    const float* wb = wtil + (size_t)b * H_ * MD;

    for (int mc = 0; mc < MD; mc += 32) {
        // stage 256 rows x 32 floats of x: coalesced global, swizzled LDS
        #pragma unroll
        for (int i = 0; i < 8; ++i) {
            int flat = i * 256 + tid;
            int sl = flat >> 3;
            int f4 = flat & 7;
            int srow = s0 + sl;
            float4 v = make_float4(0.f, 0.f, 0.f, 0.f);
            if (srow < S)
                v = *(const float4*)(xb + (size_t)srow * MD + mc + f4 * 4);
            X4[sl * 8 + (f4 ^ (sl & 7))] = v;
        }
        // stage w-tilde chunk: 16 h x 32 floats = 128 float4, threads 0..127
        if (tid < 128)
            W4[tid] = *(const float4*)(wb + (size_t)(tid >> 3) * MD + mc + (tid & 7) * 4);
        __syncthreads();

        // x chunk -> registers (8 x ds_read_b128, ~2-way max aliasing)
        float4 xr[8];
        #pragma unroll
        for (int mm4 = 0; mm4 < 8; ++mm4)
            xr[mm4] = X4[tid * 8 + (mm4 ^ (tid & 7))];

        #pragma unroll
        for (int h = 0; h < 16; ++h) {
            #pragma unroll
            for (int mm4 = 0; mm4 < 8; ++mm4) {
                float4 wv = W4[h * 8 + mm4];   // uniform addr -> broadcast, conflict-free
                acc[h] += xr[mm4].x * wv.x + xr[mm4].y * wv.y
                        + xr[mm4].z * wv.z + xr[mm4].w * wv.w;
            }
        }
        __syncthreads();
    }

    const int s = s0 + tid;
    if (s < S) {
        #pragma unroll
        for (int h = 0; h < 16; ++h)
            scores[((size_t)b * H_ + h) * sfull + s] = acc[h] * 0.125f;
    }
}

// ---- Kernel C: softmax over s + sparse gather y = attn^T x + Wv projection -
// grid (16 h, 64 b), block 256
__global__ void k_attn(const float* __restrict__ x, const float* __restrict__ scores,
                       const float* __restrict__ wv, const int* __restrict__ idxp,
                       float* __restrict__ concat, int sfull) {
    __shared__ float red[8];
    __shared__ int   scan[256];
    __shared__ int   lidx[4096];
    __shared__ float lw[4096];
    __shared__ float ylds[1024];
    __shared__ float pred[256];

    const int tid = threadIdx.x;
    const int h = blockIdx.x, b = blockIdx.y;
    const int S = *idxp + 1;
    const float* sc = scores + ((size_t)b * H_ + h) * sfull;

    float ls[16];
    float mx = -INFINITY;
    #pragma unroll
    for (int k = 0; k < 16; ++k) {
        int s = tid + 256 * k;
        if (s < S) { ls[k] = sc[s]; mx = fmaxf(mx, ls[k]); }
        else ls[k] = -INFINITY;
    }
    // block max
    mx = waveMax(mx);
    const int wid = tid >> 6, lane = tid & 63;
    if (lane == 0) red[wid] = mx;
    __syncthreads();
    mx = fmaxf(fmaxf(red[0], red[1]), fmaxf(red[2], red[3]));

    // denom + significant count (exp(s-max) <= 1.7e-15 contributes nothing)
    float sum = 0.f; int cnt = 0;
    #pragma unroll
    for (int k = 0; k < 16; ++k) {
        if (ls[k] > -INFINITY) {
            float e = ls[k] - mx;
            sum += expf(e);
            if (e > -34.f) ++cnt;
        }
    }
    sum = waveSum(sum);
    __syncthreads();
    if (lane == 0) red[4 + wid] = sum;
    __syncthreads();
    const float inv = 1.f / (red[4] + red[5] + red[6] + red[7]);

    // deterministic compaction: exclusive scan of per-thread counts
    scan[tid] = cnt;
    __syncthreads();
    for (int off = 1; off < 256; off <<= 1) {
        int v = (tid >= off) ? scan[tid - off] : 0;
        __syncthreads();
        scan[tid] += v;
        __syncthreads();
    }
    const int total = scan[255];
    int pos = scan[tid] - cnt;
    #pragma unroll
    for (int k = 0; k < 16; ++k) {
        if (ls[k] > -INFINITY) {
            float e = ls[k] - mx;
            if (e > -34.f) { lidx[pos] = tid + 256 * k; lw[pos] = expf(e) * inv; ++pos; }
        }
    }
    __syncthreads();

    // y[m] = sum_{significant s} attn * x[b,s,m]  (typically 1-3 rows)
    float4 acc = make_float4(0.f, 0.f, 0.f, 0.f);
    const float* xb = x + (size_t)b * sfull * MD;
    for (int e = 0; e < total; ++e) {
        int s = lidx[e]; float w = lw[e];
        float4 xv = *(const float4*)(xb + (size_t)s * MD + tid * 4);
        acc.x += w * xv.x; acc.y += w * xv.y; acc.z += w * xv.z; acc.w += w * xv.w;
    }
    *(float4*)(&ylds[tid * 4]) = acc;
    __syncthreads();

    // head_out[d] = sum_m y[m] * Wv[m, h*64+d]
    const int d = tid & 63, g = tid >> 6;
    const float* wcol = wv + (size_t)h * D_ + d;
    float part = 0.f;
    for (int m = g * 256; m < g * 256 + 256; ++m)
        part += ylds[m] * wcol[(size_t)m * MD];
    pred[tid] = part;
    __syncthreads();
    if (tid < 64) {
        float v = pred[tid] + pred[tid + 64] + pred[tid + 128] + pred[tid + 192];
        concat[(size_t)b * MD + h * D_ + tid] = v;
    }
}

// ---- Kernel T: fcwt[m][n] = fcW[n][m] --------------------------------------
__global__ void k_transpose(const float* __restrict__ a, float* __restrict__ at) {
    __shared__ float t[32][33];
    const int bx = blockIdx.x * 32, by = blockIdx.y * 32;
    const int tx = threadIdx.x & 31, ty = threadIdx.x >> 5;  // 32x8
    for (int r = ty; r < 32; r += 8)
        t[r][tx] = a[(size_t)(by + r) * MD + bx + tx];
    __syncthreads();
    for (int r = ty; r < 32; r += 8)
        at[(size_t)(bx + r) * MD + by + tx] = t[tx][r];
}

// ---- Kernel D: integ[b,n] = sum_m concat[b,m] * fcW[n,m] + bias[n] ---------
// grid 64 (b), block 256; rank-1 over fcwt rows (coalesced)
__global__ void k_fc(const float* __restrict__ concat, const float* __restrict__ fcwt,
                     const float* __restrict__ bias, float* __restrict__ integ) {
    __shared__ float c[1024];
    const int tid = threadIdx.x, b = blockIdx.x;
    #pragma unroll
    for (int k = 0; k < 4; ++k) c[tid + 256 * k] = concat[(size_t)b * MD + tid + 256 * k];
    __syncthreads();
    float acc[4] = {0, 0, 0, 0};
    for (int m = 0; m < MD; ++m) {
        float cm = c[m];
        #pragma unroll
        for (int k = 0; k < 4; ++k)
            acc[k] += cm * fcwt[(size_t)m * MD + tid + 256 * k];
    }
    #pragma unroll
    for (int k = 0; k < 4; ++k)
        integ[(size_t)b * MD + tid + 256 * k] = acc[k] + bias[tid + 256 * k];
}

// ---- Kernel E: LayerNorm ---------------------------------------------------
__global__ void k_ln(const float* __restrict__ integ, const float* __restrict__ gamma,
                     const float* __restrict__ beta, float* __restrict__ out) {
    __shared__ float red[8];
    const int tid = threadIdx.x, b = blockIdx.x;
    float v[4];
    #pragma unroll
    for (int k = 0; k < 4; ++k) v[k] = integ[(size_t)b * MD + tid + 256 * k];
    float s = v[0] + v[1] + v[2] + v[3];
    s = waveSum(s);
    const int wid = tid >> 6, lane = tid & 63;
    if (lane == 0) red[wid] = s;
    __syncthreads();
    const float mean = (red[0] + red[1] + red[2] + red[3]) * (1.f / MD);
    float q = 0.f;
    #pragma unroll
    for (int k = 0; k < 4; ++k) { float d = v[k] - mean; q += d * d; }
    q = waveSum(q);
    __syncthreads();
    if (lane == 0) red[4 + wid] = q;
    __syncthreads();
    const float var = (red[4] + red[5] + red[6] + red[7]) * (1.f / MD);
    const float rs = rsqrtf(var + LNEPS);
    #pragma unroll
    for (int k = 0; k < 4; ++k) {
        int i = tid + 256 * k;
        out[(size_t)b * MD + i] = (v[k] - mean) * rs * gamma[i] + beta[i];
    }
}

extern "C" void kernel_launch(void* const* d_in, const int* in_sizes, int n_in,
                              void* d_out, int out_size, void* d_ws, size_t ws_size,
                              hipStream_t stream) {
    const float* x     = (const float*)d_in[0];
    const float* wq    = (const float*)d_in[1];
    const float* wk    = (const float*)d_in[2];
    const float* wvp   = (const float*)d_in[3];
    const float* fcw   = (const float*)d_in[4];
    const float* fcb   = (const float*)d_in[5];
    const float* gamma = (const float*)d_in[6];
    const float* beta  = (const float*)d_in[7];
    const int*   idxp  = (const int*)d_in[8];
    float* out = (float*)d_out;

    const int sfull = in_sizes[0] / (B_ * MD);   // 4096

    float* q      = (float*)d_ws;
    float* wtil   = q      + (size_t)B_ * MD;
    float* scores = wtil   + (size_t)B_ * H_ * MD;
    float* concat = scores + (size_t)B_ * H_ * sfull;
    float* integ  = concat + (size_t)B_ * MD;
    float* fcwt   = integ  + (size_t)B_ * MD;

    hipLaunchKernelGGL(k_q,         dim3(4, 8),            dim3(256), 0, stream, x, wq, idxp, q, sfull);
    hipLaunchKernelGGL(k_wtil,      dim3(16, 8),           dim3(256), 0, stream, wk, q, wtil);
    hipLaunchKernelGGL(k_scores,    dim3((sfull + 255) / 256, B_), dim3(256), 0, stream, x, wtil, idxp, scores, sfull);
    hipLaunchKernelGGL(k_transpose, dim3(32, 32),          dim3(256), 0, stream, fcw, fcwt);
    hipLaunchKernelGGL(k_attn,      dim3(H_, B_),          dim3(256), 0, stream, x, scores, wvp, idxp, concat, sfull);
    hipLaunchKernelGGL(k_fc,        dim3(B_),              dim3(256), 0, stream, concat, fcwt, fcb, integ);
    hipLaunchKernelGGL(k_ln,        dim3(B_),              dim3(256), 0, stream, integ, gamma, beta, out);
}

// Round 3
// 404.567 us; speedup vs baseline: 2.3690x; 1.9523x over previous
//
#include <hip/hip_runtime.h>
#include <math.h>

#define B_   64
#define MD   1024
#define H_   16
#define D_   64
#define LNEPS 1e-5f

// ---------------------------------------------------------------------------
// ws layout (floats):
//   q      [64][1024]
//   wtil   [64][16][1024]     w̃[b,h,m] = sum_d Wk[m, h*64+d] * q[b,h,d]
//   scores [64][16][sfull]
//   concat [64][1024]
//   integ  [64][1024]
//   fcwt   [1024][1024]       fc_weight transposed
// ---------------------------------------------------------------------------

__device__ __forceinline__ float waveMax(float v) {
    #pragma unroll
    for (int off = 32; off > 0; off >>= 1) v = fmaxf(v, __shfl_xor(v, off, 64));
    return v;
}
__device__ __forceinline__ float waveSum(float v) {
    #pragma unroll
    for (int off = 32; off > 0; off >>= 1) v += __shfl_xor(v, off, 64);
    return v;
}

// ---- Kernel A: q[b, col] = sum_m x[b, idx, m] * Wq[m, col] -----------------
// grid (4 col-chunks, 64 b), block 256
__global__ void k_q(const float* __restrict__ x, const float* __restrict__ wq,
                    const int* __restrict__ idxp, float* __restrict__ qout, int sfull) {
    const int tid = threadIdx.x;
    const int col = blockIdx.x * 256 + tid;
    const int b   = blockIdx.y;
    const int idx = *idxp;
    const float* xr = x + ((size_t)b * sfull + idx) * MD;   // uniform -> scalar loads
    float a0 = 0.f, a1 = 0.f, a2 = 0.f, a3 = 0.f;
    for (int m = 0; m < MD; m += 4) {
        a0 += xr[m]     * wq[(size_t)m * MD + col];
        a1 += xr[m + 1] * wq[(size_t)(m + 1) * MD + col];
        a2 += xr[m + 2] * wq[(size_t)(m + 2) * MD + col];
        a3 += xr[m + 3] * wq[(size_t)(m + 3) * MD + col];
    }
    qout[(size_t)b * MD + col] = (a0 + a1) + (a2 + a3);
}

// ---- Kernel B: wtil[b,h,m] = sum_d Wk[m, h*64+d] * q[b, h*64+d] ------------
// grid (16 h, 8 b-groups), block 256
__global__ void k_wtil(const float* __restrict__ wk, const float* __restrict__ q,
                       float* __restrict__ wtil) {
    const int tid = threadIdx.x;
    const int h  = blockIdx.x;
    const int b0 = blockIdx.y * 8;
    for (int mi = 0; mi < 4; ++mi) {
        const int m = mi * 256 + tid;
        const float4* wrow = (const float4*)(wk + (size_t)m * MD + h * D_);
        float4 wv[16];
        #pragma unroll
        for (int j = 0; j < 16; ++j) wv[j] = wrow[j];
        #pragma unroll
        for (int bb = 0; bb < 8; ++bb) {
            const float* qh = q + (size_t)(b0 + bb) * MD + h * D_;  // uniform -> s_load
            float acc = 0.f;
            #pragma unroll
            for (int j = 0; j < 16; ++j)
                acc += wv[j].x * qh[4*j] + wv[j].y * qh[4*j+1]
                     + wv[j].z * qh[4*j+2] + wv[j].w * qh[4*j+3];
            wtil[((size_t)(b0 + bb) * H_ + h) * MD + m] = acc;
        }
    }
}

// ---- Kernel P1: scores[b,h,s] = (x[b,s,:] . wtil[b,h,:]) / 8 ---------------
// grid (sfull/256 s-tiles, 64 b), block 256. Streams all of x exactly once.
// Lane tiling: lane=(sg,hg); each thread computes a 4s x 4h register tile.
// Per wave-chunk(16m): 4 ds_writes + 16 x-reads(16-distinct) + 16 W-reads
// (4-distinct) -- minimal LDS instruction-slot usage.
__global__ __launch_bounds__(256) void k_scores(
        const float* __restrict__ x, const float* __restrict__ wtil,
        const int* __restrict__ idxp, float* __restrict__ scores, int sfull) {
    __shared__ float Xs[256 * 20];   // 20 KB: 16 data + 4 pad floats per row (2-way max bank alias)
    __shared__ float Ws[16 * 16];    // 1 KB : w-tilde[h][m-chunk]
    const int tid  = threadIdx.x;
    const int w    = tid >> 6;
    const int lane = tid & 63;
    const int sg   = lane & 15;      // s sub-index (16 distinct per read instr)
    const int hg   = lane >> 4;      // h group    (4 distinct per read instr)
    const int b    = blockIdx.y;
    const int s0   = blockIdx.x * 256;
    const int S    = *idxp + 1;
    if (s0 >= S) return;

    const float* xb = x    + (size_t)b * sfull * MD;
    const float* wb = wtil + (size_t)b * H_ * MD;

    float acc[4][4] = {};
    float4 nx[4];
    float4 nw;

#define STAGE_LOAD(MC) do {                                                        \
        _Pragma("unroll")                                                          \
        for (int i = 0; i < 4; ++i) {                                              \
            int flat = i * 256 + tid;                                              \
            int sl = flat >> 2, f4 = flat & 3;                                     \
            int srow = s0 + sl;                                                    \
            nx[i] = (srow < S)                                                     \
                ? *(const float4*)(xb + (size_t)srow * MD + (MC) + f4 * 4)         \
                : make_float4(0.f, 0.f, 0.f, 0.f);                                 \
        }                                                                          \
        if (tid < 64)                                                              \
            nw = *(const float4*)(wb + (size_t)(tid >> 2) * MD + (MC) + (tid & 3) * 4); \
    } while (0)

    STAGE_LOAD(0);

    for (int mc = 0; mc < MD; mc += 16) {
        // commit staged registers to LDS
        #pragma unroll
        for (int i = 0; i < 4; ++i) {
            int flat = i * 256 + tid;
            int sl = flat >> 2, f4 = flat & 3;
            *(float4*)(&Xs[sl * 20 + f4 * 4]) = nx[i];
        }
        if (tid < 64) *(float4*)(&Ws[(tid >> 2) * 16 + (tid & 3) * 4]) = nw;
        __syncthreads();

        if (mc + 16 < MD) STAGE_LOAD(mc + 16);   // prefetch next chunk into regs

        // W tile -> regs: 16 reads, 4 distinct addresses each (hg)
        float4 wr[4][4];
        #pragma unroll
        for (int j = 0; j < 4; ++j) {
            #pragma unroll
            for (int mm = 0; mm < 4; ++mm)
                wr[j][mm] = *(const float4*)(&Ws[(hg + 4 * j) * 16 + mm * 4]);
        }
        #pragma unroll
        for (int k = 0; k < 4; ++k) {
            const int row = w * 64 + sg + 16 * k;
            float4 xr[4];
            #pragma unroll
            for (int mm = 0; mm < 4; ++mm)
                xr[mm] = *(const float4*)(&Xs[row * 20 + mm * 4]);
            #pragma unroll
            for (int j = 0; j < 4; ++j) {
                #pragma unroll
                for (int mm = 0; mm < 4; ++mm)
                    acc[k][j] += xr[mm].x * wr[j][mm].x + xr[mm].y * wr[j][mm].y
                               + xr[mm].z * wr[j][mm].z + xr[mm].w * wr[j][mm].w;
            }
        }
        __syncthreads();
    }
#undef STAGE_LOAD

    #pragma unroll
    for (int k = 0; k < 4; ++k) {
        const int s = s0 + w * 64 + sg + 16 * k;
        if (s < S) {
            #pragma unroll
            for (int j = 0; j < 4; ++j)
                scores[((size_t)b * H_ + (hg + 4 * j)) * sfull + s] = acc[k][j] * 0.125f;
        }
    }
}

// ---- Kernel C: softmax over s + sparse gather y = attn^T x + Wv projection -
// grid (16 h, 64 b), block 256
__global__ void k_attn(const float* __restrict__ x, const float* __restrict__ scores,
                       const float* __restrict__ wv, const int* __restrict__ idxp,
                       float* __restrict__ concat, int sfull) {
    __shared__ float red[8];
    __shared__ int   scan[256];
    __shared__ int   lidx[4096];
    __shared__ float lw[4096];
    __shared__ float ylds[1024];
    __shared__ float pred[256];

    const int tid = threadIdx.x;
    const int h = blockIdx.x, b = blockIdx.y;
    const int S = *idxp + 1;
    const float* sc = scores + ((size_t)b * H_ + h) * sfull;

    float ls[16];
    float mx = -INFINITY;
    #pragma unroll
    for (int k = 0; k < 16; ++k) {
        int s = tid + 256 * k;
        if (s < S) { ls[k] = sc[s]; mx = fmaxf(mx, ls[k]); }
        else ls[k] = -INFINITY;
    }
    // block max
    mx = waveMax(mx);
    const int wid = tid >> 6, lane = tid & 63;
    if (lane == 0) red[wid] = mx;
    __syncthreads();
    mx = fmaxf(fmaxf(red[0], red[1]), fmaxf(red[2], red[3]));

    // denom + significant count (exp(s-max) <= 1.7e-15 contributes nothing)
    float sum = 0.f; int cnt = 0;
    #pragma unroll
    for (int k = 0; k < 16; ++k) {
        if (ls[k] > -INFINITY) {
            float e = ls[k] - mx;
            sum += expf(e);
            if (e > -34.f) ++cnt;
        }
    }
    sum = waveSum(sum);
    __syncthreads();
    if (lane == 0) red[4 + wid] = sum;
    __syncthreads();
    const float inv = 1.f / (red[4] + red[5] + red[6] + red[7]);

    // deterministic compaction: exclusive scan of per-thread counts
    scan[tid] = cnt;
    __syncthreads();
    for (int off = 1; off < 256; off <<= 1) {
        int v = (tid >= off) ? scan[tid - off] : 0;
        __syncthreads();
        scan[tid] += v;
        __syncthreads();
    }
    const int total = scan[255];
    int pos = scan[tid] - cnt;
    #pragma unroll
    for (int k = 0; k < 16; ++k) {
        if (ls[k] > -INFINITY) {
            float e = ls[k] - mx;
            if (e > -34.f) { lidx[pos] = tid + 256 * k; lw[pos] = expf(e) * inv; ++pos; }
        }
    }
    __syncthreads();

    // y[m] = sum_{significant s} attn * x[b,s,m]  (typically 1-3 rows)
    float4 acc = make_float4(0.f, 0.f, 0.f, 0.f);
    const float* xb = x + (size_t)b * sfull * MD;
    for (int e = 0; e < total; ++e) {
        int s = lidx[e]; float w = lw[e];
        float4 xv = *(const float4*)(xb + (size_t)s * MD + tid * 4);
        acc.x += w * xv.x; acc.y += w * xv.y; acc.z += w * xv.z; acc.w += w * xv.w;
    }
    *(float4*)(&ylds[tid * 4]) = acc;
    __syncthreads();

    // head_out[d] = sum_m y[m] * Wv[m, h*64+d]
    const int d = tid & 63, g = tid >> 6;
    const float* wcol = wv + (size_t)h * D_ + d;
    float part = 0.f;
    for (int m = g * 256; m < g * 256 + 256; ++m)
        part += ylds[m] * wcol[(size_t)m * MD];
    pred[tid] = part;
    __syncthreads();
    if (tid < 64) {
        float v = pred[tid] + pred[tid + 64] + pred[tid + 128] + pred[tid + 192];
        concat[(size_t)b * MD + h * D_ + tid] = v;
    }
}

// ---- Kernel T: fcwt[m][n] = fcW[n][m] --------------------------------------
__global__ void k_transpose(const float* __restrict__ a, float* __restrict__ at) {
    __shared__ float t[32][33];
    const int bx = blockIdx.x * 32, by = blockIdx.y * 32;
    const int tx = threadIdx.x & 31, ty = threadIdx.x >> 5;  // 32x8
    for (int r = ty; r < 32; r += 8)
        t[r][tx] = a[(size_t)(by + r) * MD + bx + tx];
    __syncthreads();
    for (int r = ty; r < 32; r += 8)
        at[(size_t)(bx + r) * MD + by + tx] = t[tx][r];
}

// ---- Kernel D: integ[b,n] = sum_m concat[b,m] * fcW[n,m] + bias[n] ---------
// grid (64 b, 4 n-chunks), block 256
__global__ void k_fc(const float* __restrict__ concat, const float* __restrict__ fcwt,
                     const float* __restrict__ bias, float* __restrict__ integ) {
    __shared__ float c[1024];
    const int tid = threadIdx.x, b = blockIdx.x;
    const int n = blockIdx.y * 256 + tid;
    #pragma unroll
    for (int k = 0; k < 4; ++k) c[tid + 256 * k] = concat[(size_t)b * MD + tid + 256 * k];
    __syncthreads();
    float a0 = 0.f, a1 = 0.f, a2 = 0.f, a3 = 0.f;
    for (int m = 0; m < MD; m += 4) {
        a0 += c[m]     * fcwt[(size_t)m * MD + n];
        a1 += c[m + 1] * fcwt[(size_t)(m + 1) * MD + n];
        a2 += c[m + 2] * fcwt[(size_t)(m + 2) * MD + n];
        a3 += c[m + 3] * fcwt[(size_t)(m + 3) * MD + n];
    }
    integ[(size_t)b * MD + n] = (a0 + a1) + (a2 + a3) + bias[n];
}

// ---- Kernel E: LayerNorm ---------------------------------------------------
__global__ void k_ln(const float* __restrict__ integ, const float* __restrict__ gamma,
                     const float* __restrict__ beta, float* __restrict__ out) {
    __shared__ float red[8];
    const int tid = threadIdx.x, b = blockIdx.x;
    float v[4];
    #pragma unroll
    for (int k = 0; k < 4; ++k) v[k] = integ[(size_t)b * MD + tid + 256 * k];
    float s = v[0] + v[1] + v[2] + v[3];
    s = waveSum(s);
    const int wid = tid >> 6, lane = tid & 63;
    if (lane == 0) red[wid] = s;
    __syncthreads();
    const float mean = (red[0] + red[1] + red[2] + red[3]) * (1.f / MD);
    float q = 0.f;
    #pragma unroll
    for (int k = 0; k < 4; ++k) { float d = v[k] - mean; q += d * d; }
    q = waveSum(q);
    __syncthreads();
    if (lane == 0) red[4 + wid] = q;
    __syncthreads();
    const float var = (red[4] + red[5] + red[6] + red[7]) * (1.f / MD);
    const float rs = rsqrtf(var + LNEPS);
    #pragma unroll
    for (int k = 0; k < 4; ++k) {
        int i = tid + 256 * k;
        out[(size_t)b * MD + i] = (v[k] - mean) * rs * gamma[i] + beta[i];
    }
}

extern "C" void kernel_launch(void* const* d_in, const int* in_sizes, int n_in,
                              void* d_out, int out_size, void* d_ws, size_t ws_size,
                              hipStream_t stream) {
    const float* x     = (const float*)d_in[0];
    const float* wq    = (const float*)d_in[1];
    const float* wk    = (const float*)d_in[2];
    const float* wvp   = (const float*)d_in[3];
    const float* fcw   = (const float*)d_in[4];
    const float* fcb   = (const float*)d_in[5];
    const float* gamma = (const float*)d_in[6];
    const float* beta  = (const float*)d_in[7];
    const int*   idxp  = (const int*)d_in[8];
    float* out = (float*)d_out;

    const int sfull = in_sizes[0] / (B_ * MD);   // 4096

    float* q      = (float*)d_ws;
    float* wtil   = q      + (size_t)B_ * MD;
    float* scores = wtil   + (size_t)B_ * H_ * MD;
    float* concat = scores + (size_t)B_ * H_ * sfull;
    float* integ  = concat + (size_t)B_ * MD;
    float* fcwt   = integ  + (size_t)B_ * MD;

    hipLaunchKernelGGL(k_q,         dim3(4, 64),           dim3(256), 0, stream, x, wq, idxp, q, sfull);
    hipLaunchKernelGGL(k_wtil,      dim3(16, 8),           dim3(256), 0, stream, wk, q, wtil);
    hipLaunchKernelGGL(k_scores,    dim3((sfull + 255) / 256, B_), dim3(256), 0, stream, x, wtil, idxp, scores, sfull);
    hipLaunchKernelGGL(k_transpose, dim3(32, 32),          dim3(256), 0, stream, fcw, fcwt);
    hipLaunchKernelGGL(k_attn,      dim3(H_, B_),          dim3(256), 0, stream, x, scores, wvp, idxp, concat, sfull);
    hipLaunchKernelGGL(k_fc,        dim3(64, 4),           dim3(256), 0, stream, concat, fcwt, fcb, integ);
    hipLaunchKernelGGL(k_ln,        dim3(B_),              dim3(256), 0, stream, integ, gamma, beta, out);
}

// Round 4
// 401.649 us; speedup vs baseline: 2.3862x; 1.0073x over previous
//
#include <hip/hip_runtime.h>
#include <math.h>

#define B_   64
#define MD   1024
#define H_   16
#define D_   64
#define LNEPS 1e-5f

// ---------------------------------------------------------------------------
// ws layout (floats):
//   q      [64][1024]
//   wtil   [64][16][1024]     w̃[b,h,m] = sum_d Wk[m, h*64+d] * q[b,h,d]
//   scores [64][16][sfull]
//   concat [64][1024]
//   integ  [64][1024]
//   fcwt   [1024][1024]       fc_weight transposed
// ---------------------------------------------------------------------------

__device__ __forceinline__ float waveMax(float v) {
    #pragma unroll
    for (int off = 32; off > 0; off >>= 1) v = fmaxf(v, __shfl_xor(v, off, 64));
    return v;
}
__device__ __forceinline__ float waveSum(float v) {
    #pragma unroll
    for (int off = 32; off > 0; off >>= 1) v += __shfl_xor(v, off, 64);
    return v;
}

// ---- Kernel A: q[b, col] = sum_m x[b, idx, m] * Wq[m, col] -----------------
// grid (4 col-chunks, 64 b), block 256
__global__ void k_q(const float* __restrict__ x, const float* __restrict__ wq,
                    const int* __restrict__ idxp, float* __restrict__ qout, int sfull) {
    const int tid = threadIdx.x;
    const int col = blockIdx.x * 256 + tid;
    const int b   = blockIdx.y;
    const int idx = *idxp;
    const float* xr = x + ((size_t)b * sfull + idx) * MD;   // uniform -> scalar loads
    float a0 = 0.f, a1 = 0.f, a2 = 0.f, a3 = 0.f;
    for (int m = 0; m < MD; m += 4) {
        a0 += xr[m]     * wq[(size_t)m * MD + col];
        a1 += xr[m + 1] * wq[(size_t)(m + 1) * MD + col];
        a2 += xr[m + 2] * wq[(size_t)(m + 2) * MD + col];
        a3 += xr[m + 3] * wq[(size_t)(m + 3) * MD + col];
    }
    qout[(size_t)b * MD + col] = (a0 + a1) + (a2 + a3);
}

// ---- Kernel B: wtil[b,h,m] = sum_d Wk[m, h*64+d] * q[b, h*64+d] ------------
// grid (16 h, 8 b-groups), block 256
__global__ void k_wtil(const float* __restrict__ wk, const float* __restrict__ q,
                       float* __restrict__ wtil) {
    const int tid = threadIdx.x;
    const int h  = blockIdx.x;
    const int b0 = blockIdx.y * 8;
    for (int mi = 0; mi < 4; ++mi) {
        const int m = mi * 256 + tid;
        const float4* wrow = (const float4*)(wk + (size_t)m * MD + h * D_);
        float4 wv[16];
        #pragma unroll
        for (int j = 0; j < 16; ++j) wv[j] = wrow[j];
        #pragma unroll
        for (int bb = 0; bb < 8; ++bb) {
            const float* qh = q + (size_t)(b0 + bb) * MD + h * D_;  // uniform -> s_load
            float acc = 0.f;
            #pragma unroll
            for (int j = 0; j < 16; ++j)
                acc += wv[j].x * qh[4*j] + wv[j].y * qh[4*j+1]
                     + wv[j].z * qh[4*j+2] + wv[j].w * qh[4*j+3];
            wtil[((size_t)(b0 + bb) * H_ + h) * MD + m] = acc;
        }
    }
}

// ---- Kernel P1: scores[b,h,s] = (x[b,s,:] . wtil[b,h,:]) / 8 ---------------
// grid (sfull/256 s-tiles, 64 b), block 256.
// v4: wave-private LDS tiles, ZERO __syncthreads. Each wave owns 64 s-rows
// (row = w*64 + sg + 16k), stages them itself, self-paced depth-1 pipeline:
//   commit regs->LDS | issue next chunk's global loads | compute (ds+FMA).
// Same-wave DS ordering + compiler waitcnts give correctness; waves never
// couple, so no barrier drain. LDS read/write addrs are chunk-invariant.
__global__ __launch_bounds__(256) void k_scores(
        const float* __restrict__ x, const float* __restrict__ wtil,
        const int* __restrict__ idxp, float* __restrict__ scores, int sfull) {
    __shared__ float Xw[4][64 * 20];   // per-wave: 64 rows x 16 m (+4 pad) = 5 KB
    __shared__ float Ww[4][16 * 20];   // per-wave: 16 h x 16 m (+4 pad) = 1.25 KB
    const int tid  = threadIdx.x;
    const int w    = tid >> 6;
    const int lane = tid & 63;
    const int sg   = lane & 15;      // s sub-index
    const int hg   = lane >> 4;      // h group
    const int b    = blockIdx.y;
    const int sblk = blockIdx.x * 256;
    const int s0   = sblk + w * 64;  // this wave's first row
    const int S    = *idxp + 1;
    if (sblk >= S) return;

    const float* xb = x    + (size_t)b * sfull * MD;
    const float* wb = wtil + (size_t)b * H_ * MD;

    float* Xs = Xw[w];
    float* Ws = Ww[w];

    const int csl = lane >> 2;       // 0..15 staging row within group
    const int cf4 = lane & 3;        // 0..3 float4 slot

    float acc[4][4] = {};
    float4 nx[4];
    float4 nw;

#define ISSUE(MC) do {                                                         \
        _Pragma("unroll")                                                      \
        for (int i = 0; i < 4; ++i) {                                          \
            int sl = i * 16 + csl;                                             \
            int srow = s0 + sl;                                                \
            nx[i] = (srow < S)                                                 \
                ? *(const float4*)(xb + (size_t)srow * MD + (MC) + cf4 * 4)    \
                : make_float4(0.f, 0.f, 0.f, 0.f);                             \
        }                                                                      \
        nw = *(const float4*)(wb + (size_t)csl * MD + (MC) + cf4 * 4);         \
    } while (0)

    ISSUE(0);

    for (int mc = 0; mc < MD; mc += 16) {
        // commit staged regs to this wave's LDS slice (in-order after last
        // chunk's ds_reads; wave-private so no cross-wave hazard)
        #pragma unroll
        for (int i = 0; i < 4; ++i)
            *(float4*)(&Xs[(i * 16 + csl) * 20 + cf4 * 4]) = nx[i];
        *(float4*)(&Ws[csl * 20 + cf4 * 4]) = nw;

        if (mc + 16 < MD) ISSUE(mc + 16);   // prefetch next chunk into regs

        // compute 4s x 4h x 16m, in two 8-m halves to cap register pressure
        #pragma unroll
        for (int half = 0; half < 2; ++half) {
            float4 wrh[4][2];
            #pragma unroll
            for (int j = 0; j < 4; ++j) {
                #pragma unroll
                for (int mm = 0; mm < 2; ++mm)
                    wrh[j][mm] = *(const float4*)(&Ws[(hg + 4 * j) * 20 + (half * 2 + mm) * 4]);
            }
            #pragma unroll
            for (int k = 0; k < 4; ++k) {
                const float4 xr0 = *(const float4*)(&Xs[(sg + 16 * k) * 20 + (half * 2) * 4]);
                const float4 xr1 = *(const float4*)(&Xs[(sg + 16 * k) * 20 + (half * 2 + 1) * 4]);
                #pragma unroll
                for (int j = 0; j < 4; ++j) {
                    acc[k][j] += xr0.x * wrh[j][0].x + xr0.y * wrh[j][0].y
                               + xr0.z * wrh[j][0].z + xr0.w * wrh[j][0].w
                               + xr1.x * wrh[j][1].x + xr1.y * wrh[j][1].y
                               + xr1.z * wrh[j][1].z + xr1.w * wrh[j][1].w;
                }
            }
        }
    }
#undef ISSUE

    #pragma unroll
    for (int k = 0; k < 4; ++k) {
        const int s = s0 + sg + 16 * k;
        if (s < S) {
            #pragma unroll
            for (int j = 0; j < 4; ++j)
                scores[((size_t)b * H_ + (hg + 4 * j)) * sfull + s] = acc[k][j] * 0.125f;
        }
    }
}

// ---- Kernel C: softmax over s + sparse gather y = attn^T x + Wv projection -
// grid (16 h, 64 b), block 256
__global__ void k_attn(const float* __restrict__ x, const float* __restrict__ scores,
                       const float* __restrict__ wv, const int* __restrict__ idxp,
                       float* __restrict__ concat, int sfull) {
    __shared__ float red[8];
    __shared__ int   scan[256];
    __shared__ int   lidx[4096];
    __shared__ float lw[4096];
    __shared__ float ylds[1024];
    __shared__ float pred[256];

    const int tid = threadIdx.x;
    const int h = blockIdx.x, b = blockIdx.y;
    const int S = *idxp + 1;
    const float* sc = scores + ((size_t)b * H_ + h) * sfull;

    float ls[16];
    float mx = -INFINITY;
    #pragma unroll
    for (int k = 0; k < 16; ++k) {
        int s = tid + 256 * k;
        if (s < S) { ls[k] = sc[s]; mx = fmaxf(mx, ls[k]); }
        else ls[k] = -INFINITY;
    }
    // block max
    mx = waveMax(mx);
    const int wid = tid >> 6, lane = tid & 63;
    if (lane == 0) red[wid] = mx;
    __syncthreads();
    mx = fmaxf(fmaxf(red[0], red[1]), fmaxf(red[2], red[3]));

    // denom + significant count (exp(s-max) <= 1.7e-15 contributes nothing)
    float sum = 0.f; int cnt = 0;
    #pragma unroll
    for (int k = 0; k < 16; ++k) {
        if (ls[k] > -INFINITY) {
            float e = ls[k] - mx;
            sum += expf(e);
            if (e > -34.f) ++cnt;
        }
    }
    sum = waveSum(sum);
    __syncthreads();
    if (lane == 0) red[4 + wid] = sum;
    __syncthreads();
    const float inv = 1.f / (red[4] + red[5] + red[6] + red[7]);

    // deterministic compaction: exclusive scan of per-thread counts
    scan[tid] = cnt;
    __syncthreads();
    for (int off = 1; off < 256; off <<= 1) {
        int v = (tid >= off) ? scan[tid - off] : 0;
        __syncthreads();
        scan[tid] += v;
        __syncthreads();
    }
    const int total = scan[255];
    int pos = scan[tid] - cnt;
    #pragma unroll
    for (int k = 0; k < 16; ++k) {
        if (ls[k] > -INFINITY) {
            float e = ls[k] - mx;
            if (e > -34.f) { lidx[pos] = tid + 256 * k; lw[pos] = expf(e) * inv; ++pos; }
        }
    }
    __syncthreads();

    // y[m] = sum_{significant s} attn * x[b,s,m]  (typically 1-3 rows)
    float4 acc = make_float4(0.f, 0.f, 0.f, 0.f);
    const float* xb = x + (size_t)b * sfull * MD;
    for (int e = 0; e < total; ++e) {
        int s = lidx[e]; float w = lw[e];
        float4 xv = *(const float4*)(xb + (size_t)s * MD + tid * 4);
        acc.x += w * xv.x; acc.y += w * xv.y; acc.z += w * xv.z; acc.w += w * xv.w;
    }
    *(float4*)(&ylds[tid * 4]) = acc;
    __syncthreads();

    // head_out[d] = sum_m y[m] * Wv[m, h*64+d]
    const int d = tid & 63, g = tid >> 6;
    const float* wcol = wv + (size_t)h * D_ + d;
    float part = 0.f;
    for (int m = g * 256; m < g * 256 + 256; ++m)
        part += ylds[m] * wcol[(size_t)m * MD];
    pred[tid] = part;
    __syncthreads();
    if (tid < 64) {
        float v = pred[tid] + pred[tid + 64] + pred[tid + 128] + pred[tid + 192];
        concat[(size_t)b * MD + h * D_ + tid] = v;
    }
}

// ---- Kernel T: fcwt[m][n] = fcW[n][m] --------------------------------------
__global__ void k_transpose(const float* __restrict__ a, float* __restrict__ at) {
    __shared__ float t[32][33];
    const int bx = blockIdx.x * 32, by = blockIdx.y * 32;
    const int tx = threadIdx.x & 31, ty = threadIdx.x >> 5;  // 32x8
    for (int r = ty; r < 32; r += 8)
        t[r][tx] = a[(size_t)(by + r) * MD + bx + tx];
    __syncthreads();
    for (int r = ty; r < 32; r += 8)
        at[(size_t)(bx + r) * MD + by + tx] = t[tx][r];
}

// ---- Kernel D: integ[b,n] = sum_m concat[b,m] * fcW[n,m] + bias[n] ---------
// grid (64 b, 4 n-chunks), block 256
__global__ void k_fc(const float* __restrict__ concat, const float* __restrict__ fcwt,
                     const float* __restrict__ bias, float* __restrict__ integ) {
    __shared__ float c[1024];
    const int tid = threadIdx.x, b = blockIdx.x;
    const int n = blockIdx.y * 256 + tid;
    #pragma unroll
    for (int k = 0; k < 4; ++k) c[tid + 256 * k] = concat[(size_t)b * MD + tid + 256 * k];
    __syncthreads();
    float a0 = 0.f, a1 = 0.f, a2 = 0.f, a3 = 0.f;
    for (int m = 0; m < MD; m += 4) {
        a0 += c[m]     * fcwt[(size_t)m * MD + n];
        a1 += c[m + 1] * fcwt[(size_t)(m + 1) * MD + n];
        a2 += c[m + 2] * fcwt[(size_t)(m + 2) * MD + n];
        a3 += c[m + 3] * fcwt[(size_t)(m + 3) * MD + n];
    }
    integ[(size_t)b * MD + n] = (a0 + a1) + (a2 + a3) + bias[n];
}

// ---- Kernel E: LayerNorm ---------------------------------------------------
__global__ void k_ln(const float* __restrict__ integ, const float* __restrict__ gamma,
                     const float* __restrict__ beta, float* __restrict__ out) {
    __shared__ float red[8];
    const int tid = threadIdx.x, b = blockIdx.x;
    float v[4];
    #pragma unroll
    for (int k = 0; k < 4; ++k) v[k] = integ[(size_t)b * MD + tid + 256 * k];
    float s = v[0] + v[1] + v[2] + v[3];
    s = waveSum(s);
    const int wid = tid >> 6, lane = tid & 63;
    if (lane == 0) red[wid] = s;
    __syncthreads();
    const float mean = (red[0] + red[1] + red[2] + red[3]) * (1.f / MD);
    float q = 0.f;
    #pragma unroll
    for (int k = 0; k < 4; ++k) { float d = v[k] - mean; q += d * d; }
    q = waveSum(q);
    __syncthreads();
    if (lane == 0) red[4 + wid] = q;
    __syncthreads();
    const float var = (red[4] + red[5] + red[6] + red[7]) * (1.f / MD);
    const float rs = rsqrtf(var + LNEPS);
    #pragma unroll
    for (int k = 0; k < 4; ++k) {
        int i = tid + 256 * k;
        out[(size_t)b * MD + i] = (v[k] - mean) * rs * gamma[i] + beta[i];
    }
}

extern "C" void kernel_launch(void* const* d_in, const int* in_sizes, int n_in,
                              void* d_out, int out_size, void* d_ws, size_t ws_size,
                              hipStream_t stream) {
    const float* x     = (const float*)d_in[0];
    const float* wq    = (const float*)d_in[1];
    const float* wk    = (const float*)d_in[2];
    const float* wvp   = (const float*)d_in[3];
    const float* fcw   = (const float*)d_in[4];
    const float* fcb   = (const float*)d_in[5];
    const float* gamma = (const float*)d_in[6];
    const float* beta  = (const float*)d_in[7];
    const int*   idxp  = (const int*)d_in[8];
    float* out = (float*)d_out;

    const int sfull = in_sizes[0] / (B_ * MD);   // 4096

    float* q      = (float*)d_ws;
    float* wtil   = q      + (size_t)B_ * MD;
    float* scores = wtil   + (size_t)B_ * H_ * MD;
    float* concat = scores + (size_t)B_ * H_ * sfull;
    float* integ  = concat + (size_t)B_ * MD;
    float* fcwt   = integ  + (size_t)B_ * MD;

    hipLaunchKernelGGL(k_q,         dim3(4, 64),           dim3(256), 0, stream, x, wq, idxp, q, sfull);
    hipLaunchKernelGGL(k_wtil,      dim3(16, 8),           dim3(256), 0, stream, wk, q, wtil);
    hipLaunchKernelGGL(k_scores,    dim3((sfull + 255) / 256, B_), dim3(256), 0, stream, x, wtil, idxp, scores, sfull);
    hipLaunchKernelGGL(k_transpose, dim3(32, 32),          dim3(256), 0, stream, fcw, fcwt);
    hipLaunchKernelGGL(k_attn,      dim3(H_, B_),          dim3(256), 0, stream, x, scores, wvp, idxp, concat, sfull);
    hipLaunchKernelGGL(k_fc,        dim3(64, 4),           dim3(256), 0, stream, concat, fcwt, fcb, integ);
    hipLaunchKernelGGL(k_ln,        dim3(B_),              dim3(256), 0, stream, integ, gamma, beta, out);
}

// Round 5
// 385.035 us; speedup vs baseline: 2.4891x; 1.0431x over previous
//
#include <hip/hip_runtime.h>
#include <math.h>

#define B_   64
#define MD   1024
#define H_   16
#define D_   64
#define LNEPS 1e-5f

// ---------------------------------------------------------------------------
// ws layout (floats):
//   q      [64][1024]
//   wtil   [64][16][1024]     w̃[b,h,m] = sum_d Wk[m, h*64+d] * q[b,h,d]
//   scores [64][16][sfull]
//   concat [64][1024]
//   integ  [64][1024]
//   fcwt   [1024][1024]       fc_weight transposed
// ---------------------------------------------------------------------------

__device__ __forceinline__ float waveMax(float v) {
    #pragma unroll
    for (int off = 32; off > 0; off >>= 1) v = fmaxf(v, __shfl_xor(v, off, 64));
    return v;
}
__device__ __forceinline__ float waveSum(float v) {
    #pragma unroll
    for (int off = 32; off > 0; off >>= 1) v += __shfl_xor(v, off, 64);
    return v;
}

// ---- Kernel A: q[b, col] = sum_m x[b, idx, m] * Wq[m, col] -----------------
// grid (4 col-chunks, 64 b), block 256
__global__ void k_q(const float* __restrict__ x, const float* __restrict__ wq,
                    const int* __restrict__ idxp, float* __restrict__ qout, int sfull) {
    const int tid = threadIdx.x;
    const int col = blockIdx.x * 256 + tid;
    const int b   = blockIdx.y;
    const int idx = *idxp;
    const float* xr = x + ((size_t)b * sfull + idx) * MD;   // uniform -> scalar loads
    float a0 = 0.f, a1 = 0.f, a2 = 0.f, a3 = 0.f;
    for (int m = 0; m < MD; m += 4) {
        a0 += xr[m]     * wq[(size_t)m * MD + col];
        a1 += xr[m + 1] * wq[(size_t)(m + 1) * MD + col];
        a2 += xr[m + 2] * wq[(size_t)(m + 2) * MD + col];
        a3 += xr[m + 3] * wq[(size_t)(m + 3) * MD + col];
    }
    qout[(size_t)b * MD + col] = (a0 + a1) + (a2 + a3);
}

// ---- Kernel B: wtil[b,h,m] = sum_d Wk[m, h*64+d] * q[b, h*64+d] ------------
// grid (16 h, 8 b-groups), block 256
__global__ void k_wtil(const float* __restrict__ wk, const float* __restrict__ q,
                       float* __restrict__ wtil) {
    const int tid = threadIdx.x;
    const int h  = blockIdx.x;
    const int b0 = blockIdx.y * 8;
    for (int mi = 0; mi < 4; ++mi) {
        const int m = mi * 256 + tid;
        const float4* wrow = (const float4*)(wk + (size_t)m * MD + h * D_);
        float4 wv[16];
        #pragma unroll
        for (int j = 0; j < 16; ++j) wv[j] = wrow[j];
        #pragma unroll
        for (int bb = 0; bb < 8; ++bb) {
            const float* qh = q + (size_t)(b0 + bb) * MD + h * D_;  // uniform -> s_load
            float acc = 0.f;
            #pragma unroll
            for (int j = 0; j < 16; ++j)
                acc += wv[j].x * qh[4*j] + wv[j].y * qh[4*j+1]
                     + wv[j].z * qh[4*j+2] + wv[j].w * qh[4*j+3];
            wtil[((size_t)(b0 + bb) * H_ + h) * MD + m] = acc;
        }
    }
}

// ---- Kernel P1: scores[b,h,s] = (x[b,s,:] . wtil[b,h,:]) / 8 ---------------
// grid (sfull/512 s-tiles, 64 b), block 256.
// v5: wave-private LDS, zero barriers, k=8 rows/thread (wave owns 128 rows).
// Per chunk/wave: 9 ds_writes + 48 ds_reads feed 512 FMAs -- LDS-op/FMA
// ratio halved vs v4 so the per-CU LDS pipe stays below the HBM stream cost.
__global__ __launch_bounds__(256) void k_scores(
        const float* __restrict__ x, const float* __restrict__ wtil,
        const int* __restrict__ idxp, float* __restrict__ scores, int sfull) {
    __shared__ float Xw[4][128 * 20];  // per-wave: 128 rows x 16 m (+4 pad) = 10 KB
    __shared__ float Ww[4][16 * 20];   // per-wave: 16 h x 16 m (+4 pad) = 1.25 KB
    const int tid  = threadIdx.x;
    const int w    = tid >> 6;
    const int lane = tid & 63;
    const int sg   = lane & 15;      // s sub-index
    const int hg   = lane >> 4;      // h group
    const int b    = blockIdx.y;
    const int sblk = blockIdx.x * 512;
    const int s0   = sblk + w * 128; // this wave's first row
    const int S    = *idxp + 1;
    if (sblk >= S) return;

    const float* xb = x    + (size_t)b * sfull * MD;
    const float* wb = wtil + (size_t)b * H_ * MD;

    float* Xs = Xw[w];
    float* Ws = Ww[w];

    const int csl = lane >> 2;       // 0..15 staging row within group
    const int cf4 = lane & 3;        // 0..3 float4 slot

    float acc[8][4] = {};
    float4 nx[8];
    float4 nw;

#define ISSUE(MC) do {                                                         \
        _Pragma("unroll")                                                      \
        for (int i = 0; i < 8; ++i) {                                          \
            int sl = i * 16 + csl;                                             \
            int srow = s0 + sl;                                                \
            nx[i] = (srow < S)                                                 \
                ? *(const float4*)(xb + (size_t)srow * MD + (MC) + cf4 * 4)    \
                : make_float4(0.f, 0.f, 0.f, 0.f);                             \
        }                                                                      \
        nw = *(const float4*)(wb + (size_t)csl * MD + (MC) + cf4 * 4);         \
    } while (0)

    ISSUE(0);

    for (int mc = 0; mc < MD; mc += 16) {
        // commit staged regs to this wave's LDS slice (in-order after last
        // chunk's ds_reads; wave-private so no cross-wave hazard)
        #pragma unroll
        for (int i = 0; i < 8; ++i)
            *(float4*)(&Xs[(i * 16 + csl) * 20 + cf4 * 4]) = nx[i];
        *(float4*)(&Ws[csl * 20 + cf4 * 4]) = nw;

        if (mc + 16 < MD) ISSUE(mc + 16);   // prefetch next chunk into regs

        // compute 8s x 4h x 16m, in two 8-m halves to cap register pressure
        #pragma unroll
        for (int half = 0; half < 2; ++half) {
            float4 wrh[4][2];
            #pragma unroll
            for (int j = 0; j < 4; ++j) {
                #pragma unroll
                for (int mm = 0; mm < 2; ++mm)
                    wrh[j][mm] = *(const float4*)(&Ws[(hg + 4 * j) * 20 + (half * 2 + mm) * 4]);
            }
            #pragma unroll
            for (int k = 0; k < 8; ++k) {
                const float4 xr0 = *(const float4*)(&Xs[(sg + 16 * k) * 20 + (half * 2) * 4]);
                const float4 xr1 = *(const float4*)(&Xs[(sg + 16 * k) * 20 + (half * 2 + 1) * 4]);
                #pragma unroll
                for (int j = 0; j < 4; ++j) {
                    acc[k][j] += xr0.x * wrh[j][0].x + xr0.y * wrh[j][0].y
                               + xr0.z * wrh[j][0].z + xr0.w * wrh[j][0].w
                               + xr1.x * wrh[j][1].x + xr1.y * wrh[j][1].y
                               + xr1.z * wrh[j][1].z + xr1.w * wrh[j][1].w;
                }
            }
        }
    }
#undef ISSUE

    #pragma unroll
    for (int k = 0; k < 8; ++k) {
        const int s = s0 + sg + 16 * k;
        if (s < S) {
            #pragma unroll
            for (int j = 0; j < 4; ++j)
                scores[((size_t)b * H_ + (hg + 4 * j)) * sfull + s] = acc[k][j] * 0.125f;
        }
    }
}

// ---- Kernel C: softmax over s + sparse gather y = attn^T x + Wv projection -
// grid (16 h, 64 b), block 256
__global__ void k_attn(const float* __restrict__ x, const float* __restrict__ scores,
                       const float* __restrict__ wv, const int* __restrict__ idxp,
                       float* __restrict__ concat, int sfull) {
    __shared__ float red[8];
    __shared__ int   scan[256];
    __shared__ int   lidx[4096];
    __shared__ float lw[4096];
    __shared__ float ylds[1024];
    __shared__ float pred[256];

    const int tid = threadIdx.x;
    const int h = blockIdx.x, b = blockIdx.y;
    const int S = *idxp + 1;
    const float* sc = scores + ((size_t)b * H_ + h) * sfull;

    float ls[16];
    float mx = -INFINITY;
    #pragma unroll
    for (int k = 0; k < 16; ++k) {
        int s = tid + 256 * k;
        if (s < S) { ls[k] = sc[s]; mx = fmaxf(mx, ls[k]); }
        else ls[k] = -INFINITY;
    }
    // block max
    mx = waveMax(mx);
    const int wid = tid >> 6, lane = tid & 63;
    if (lane == 0) red[wid] = mx;
    __syncthreads();
    mx = fmaxf(fmaxf(red[0], red[1]), fmaxf(red[2], red[3]));

    // denom + significant count (exp(s-max) <= 1.7e-15 contributes nothing)
    float sum = 0.f; int cnt = 0;
    #pragma unroll
    for (int k = 0; k < 16; ++k) {
        if (ls[k] > -INFINITY) {
            float e = ls[k] - mx;
            sum += expf(e);
            if (e > -34.f) ++cnt;
        }
    }
    sum = waveSum(sum);
    __syncthreads();
    if (lane == 0) red[4 + wid] = sum;
    __syncthreads();
    const float inv = 1.f / (red[4] + red[5] + red[6] + red[7]);

    // deterministic compaction: exclusive scan of per-thread counts
    scan[tid] = cnt;
    __syncthreads();
    for (int off = 1; off < 256; off <<= 1) {
        int v = (tid >= off) ? scan[tid - off] : 0;
        __syncthreads();
        scan[tid] += v;
        __syncthreads();
    }
    const int total = scan[255];
    int pos = scan[tid] - cnt;
    #pragma unroll
    for (int k = 0; k < 16; ++k) {
        if (ls[k] > -INFINITY) {
            float e = ls[k] - mx;
            if (e > -34.f) { lidx[pos] = tid + 256 * k; lw[pos] = expf(e) * inv; ++pos; }
        }
    }
    __syncthreads();

    // y[m] = sum_{significant s} attn * x[b,s,m]  (typically 1-3 rows)
    float4 acc = make_float4(0.f, 0.f, 0.f, 0.f);
    const float* xb = x + (size_t)b * sfull * MD;
    for (int e = 0; e < total; ++e) {
        int s = lidx[e]; float w = lw[e];
        float4 xv = *(const float4*)(xb + (size_t)s * MD + tid * 4);
        acc.x += w * xv.x; acc.y += w * xv.y; acc.z += w * xv.z; acc.w += w * xv.w;
    }
    *(float4*)(&ylds[tid * 4]) = acc;
    __syncthreads();

    // head_out[d] = sum_m y[m] * Wv[m, h*64+d]
    const int d = tid & 63, g = tid >> 6;
    const float* wcol = wv + (size_t)h * D_ + d;
    float part = 0.f;
    for (int m = g * 256; m < g * 256 + 256; ++m)
        part += ylds[m] * wcol[(size_t)m * MD];
    pred[tid] = part;
    __syncthreads();
    if (tid < 64) {
        float v = pred[tid] + pred[tid + 64] + pred[tid + 128] + pred[tid + 192];
        concat[(size_t)b * MD + h * D_ + tid] = v;
    }
}

// ---- Kernel T: fcwt[m][n] = fcW[n][m] --------------------------------------
__global__ void k_transpose(const float* __restrict__ a, float* __restrict__ at) {
    __shared__ float t[32][33];
    const int bx = blockIdx.x * 32, by = blockIdx.y * 32;
    const int tx = threadIdx.x & 31, ty = threadIdx.x >> 5;  // 32x8
    for (int r = ty; r < 32; r += 8)
        t[r][tx] = a[(size_t)(by + r) * MD + bx + tx];
    __syncthreads();
    for (int r = ty; r < 32; r += 8)
        at[(size_t)(bx + r) * MD + by + tx] = t[tx][r];
}

// ---- Kernel D: integ[b,n] = sum_m concat[b,m] * fcW[n,m] + bias[n] ---------
// grid (64 b, 4 n-chunks), block 256
__global__ void k_fc(const float* __restrict__ concat, const float* __restrict__ fcwt,
                     const float* __restrict__ bias, float* __restrict__ integ) {
    __shared__ float c[1024];
    const int tid = threadIdx.x, b = blockIdx.x;
    const int n = blockIdx.y * 256 + tid;
    #pragma unroll
    for (int k = 0; k < 4; ++k) c[tid + 256 * k] = concat[(size_t)b * MD + tid + 256 * k];
    __syncthreads();
    float a0 = 0.f, a1 = 0.f, a2 = 0.f, a3 = 0.f;
    for (int m = 0; m < MD; m += 4) {
        a0 += c[m]     * fcwt[(size_t)m * MD + n];
        a1 += c[m + 1] * fcwt[(size_t)(m + 1) * MD + n];
        a2 += c[m + 2] * fcwt[(size_t)(m + 2) * MD + n];
        a3 += c[m + 3] * fcwt[(size_t)(m + 3) * MD + n];
    }
    integ[(size_t)b * MD + n] = (a0 + a1) + (a2 + a3) + bias[n];
}

// ---- Kernel E: LayerNorm ---------------------------------------------------
__global__ void k_ln(const float* __restrict__ integ, const float* __restrict__ gamma,
                     const float* __restrict__ beta, float* __restrict__ out) {
    __shared__ float red[8];
    const int tid = threadIdx.x, b = blockIdx.x;
    float v[4];
    #pragma unroll
    for (int k = 0; k < 4; ++k) v[k] = integ[(size_t)b * MD + tid + 256 * k];
    float s = v[0] + v[1] + v[2] + v[3];
    s = waveSum(s);
    const int wid = tid >> 6, lane = tid & 63;
    if (lane == 0) red[wid] = s;
    __syncthreads();
    const float mean = (red[0] + red[1] + red[2] + red[3]) * (1.f / MD);
    float q = 0.f;
    #pragma unroll
    for (int k = 0; k < 4; ++k) { float d = v[k] - mean; q += d * d; }
    q = waveSum(q);
    __syncthreads();
    if (lane == 0) red[4 + wid] = q;
    __syncthreads();
    const float var = (red[4] + red[5] + red[6] + red[7]) * (1.f / MD);
    const float rs = rsqrtf(var + LNEPS);
    #pragma unroll
    for (int k = 0; k < 4; ++k) {
        int i = tid + 256 * k;
        out[(size_t)b * MD + i] = (v[k] - mean) * rs * gamma[i] + beta[i];
    }
}

extern "C" void kernel_launch(void* const* d_in, const int* in_sizes, int n_in,
                              void* d_out, int out_size, void* d_ws, size_t ws_size,
                              hipStream_t stream) {
    const float* x     = (const float*)d_in[0];
    const float* wq    = (const float*)d_in[1];
    const float* wk    = (const float*)d_in[2];
    const float* wvp   = (const float*)d_in[3];
    const float* fcw   = (const float*)d_in[4];
    const float* fcb   = (const float*)d_in[5];
    const float* gamma = (const float*)d_in[6];
    const float* beta  = (const float*)d_in[7];
    const int*   idxp  = (const int*)d_in[8];
    float* out = (float*)d_out;

    const int sfull = in_sizes[0] / (B_ * MD);   // 4096

    float* q      = (float*)d_ws;
    float* wtil   = q      + (size_t)B_ * MD;
    float* scores = wtil   + (size_t)B_ * H_ * MD;
    float* concat = scores + (size_t)B_ * H_ * sfull;
    float* integ  = concat + (size_t)B_ * MD;
    float* fcwt   = integ  + (size_t)B_ * MD;

    hipLaunchKernelGGL(k_q,         dim3(4, 64),           dim3(256), 0, stream, x, wq, idxp, q, sfull);
    hipLaunchKernelGGL(k_wtil,      dim3(16, 8),           dim3(256), 0, stream, wk, q, wtil);
    hipLaunchKernelGGL(k_scores,    dim3((sfull + 511) / 512, B_), dim3(256), 0, stream, x, wtil, idxp, scores, sfull);
    hipLaunchKernelGGL(k_transpose, dim3(32, 32),          dim3(256), 0, stream, fcw, fcwt);
    hipLaunchKernelGGL(k_attn,      dim3(H_, B_),          dim3(256), 0, stream, x, scores, wvp, idxp, concat, sfull);
    hipLaunchKernelGGL(k_fc,        dim3(64, 4),           dim3(256), 0, stream, concat, fcwt, fcb, integ);
    hipLaunchKernelGGL(k_ln,        dim3(B_),              dim3(256), 0, stream, integ, gamma, beta, out);
}